// Round 1
// baseline (854.836 us; speedup 1.0000x reference)
//
#include <hip/hip_runtime.h>

// RSFConv2d: (1) synthesize 32x32x3x3 kernel from freq_weight via irfft2 +
// 32-way rot/scale grid-sample average; (2) 3x3 pad=1 fp32 conv on (8,32,512,512).

#define KSZ 3

// ---------------- kernel synthesis: one thread per (o,i) pair ----------------
__global__ __launch_bounds__(256) void prep_kernel(const float* __restrict__ fw,
                                                   float* __restrict__ kw)
{
    int gid = blockIdx.x * blockDim.x + threadIdx.x;
    if (gid >= 32 * 32) return;
    int o = gid >> 5;
    int i = gid & 31;

    // freq_weight[o][i][ky(3)][kx(2)][reim(2)]
    const float* f = fw + (size_t)gid * 12;
    float re[3][2], im[3][2];
#pragma unroll
    for (int ky = 0; ky < 3; ++ky)
#pragma unroll
        for (int kx = 0; kx < 2; ++kx) {
            re[ky][kx] = f[(ky * 2 + kx) * 2 + 0];
            im[ky][kx] = f[(ky * 2 + kx) * 2 + 1];
        }

    // irfft2 to 3x3: out[y][x] = (1/9) * Re sum_{ky,kx=0..2} Cf[ky][kx] e^{+2pi i (ky*y+kx*x)/3}
    // Cf[ky][2] = conj(C[(3-ky)%3][1]) (Hermitian extension of the rfft axis).
    const float c3[3] = {1.f, -0.5f, -0.5f};
    const float s3[3] = {0.f, 0.86602540378443864676f, -0.86602540378443864676f};

    float base[3][3];
#pragma unroll
    for (int y = 0; y < 3; ++y)
#pragma unroll
        for (int x = 0; x < 3; ++x) {
            float sum = 0.f;
#pragma unroll
            for (int ky = 0; ky < 3; ++ky)
#pragma unroll
                for (int kx = 0; kx < 3; ++kx) {
                    float rf, mf;
                    if (kx < 2) {
                        rf = re[ky][kx];
                        mf = im[ky][kx];
                    } else {
                        int kys = (3 - ky) % 3;  // (−ky) mod 3
                        rf = re[kys][1];
                        mf = -im[kys][1];
                    }
                    int m = (ky * y + kx * x) % 3;
                    sum += rf * c3[m] - mf * s3[m];
                }
            base[y][x] = sum * (1.f / 9.f);
        }

    // 32 rotation/scale transforms (affine_grid + grid_sample bilinear,
    // zeros padding, align_corners=False), averaged.
    const float scales[4] = {1.f, 1.25f, 1.5625f, 1.953125f};
    const float coords[3] = {-2.f / 3.f, 0.f, 2.f / 3.f};

    float acc[3][3] = {{0.f, 0.f, 0.f}, {0.f, 0.f, 0.f}, {0.f, 0.f, 0.f}};

    for (int t = 0; t < 32; ++t) {
        int r = t >> 2, si = t & 3;
        float th = (float)r * 0.78539816339744830961f;
        float sc = scales[si];
        float c = cosf(th) * sc;
        float s = sinf(th) * sc;
#pragma unroll
        for (int p = 0; p < 3; ++p) {
#pragma unroll
            for (int q = 0; q < 3; ++q) {
                float gxo = coords[q], gyo = coords[p];
                float gx = c * gxo - s * gyo;
                float gy = s * gxo + c * gyo;
                float ix = ((gx + 1.f) * 3.f - 1.f) * 0.5f;
                float iy = ((gy + 1.f) * 3.f - 1.f) * 0.5f;
                float fx0 = floorf(ix), fy0 = floorf(iy);
                int x0 = (int)fx0, y0 = (int)fy0;
                int x1 = x0 + 1, y1 = y0 + 1;
                float wx1 = ix - fx0, wy1 = iy - fy0;
                float wx0 = 1.f - wx1, wy0 = 1.f - wy1;

                float v = 0.f;
                {
                    int yc = min(max(y0, 0), 2), xc = min(max(x0, 0), 2);
                    bool ok = (x0 >= 0) & (x0 < 3) & (y0 >= 0) & (y0 < 3);
                    v += (ok ? base[yc][xc] : 0.f) * (wy0 * wx0);
                }
                {
                    int yc = min(max(y0, 0), 2), xc = min(max(x1, 0), 2);
                    bool ok = (x1 >= 0) & (x1 < 3) & (y0 >= 0) & (y0 < 3);
                    v += (ok ? base[yc][xc] : 0.f) * (wy0 * wx1);
                }
                {
                    int yc = min(max(y1, 0), 2), xc = min(max(x0, 0), 2);
                    bool ok = (x0 >= 0) & (x0 < 3) & (y1 >= 0) & (y1 < 3);
                    v += (ok ? base[yc][xc] : 0.f) * (wy1 * wx0);
                }
                {
                    int yc = min(max(y1, 0), 2), xc = min(max(x1, 0), 2);
                    bool ok = (x1 >= 0) & (x1 < 3) & (y1 >= 0) & (y1 < 3);
                    v += (ok ? base[yc][xc] : 0.f) * (wy1 * wx1);
                }
                acc[p][q] += v;
            }
        }
    }

    // store in [i][dy][dx][o] layout for block-uniform scalar loads in conv
#pragma unroll
    for (int p = 0; p < 3; ++p)
#pragma unroll
        for (int q = 0; q < 3; ++q)
            kw[(((i * 3 + p) * 3 + q) << 5) + o] = acc[p][q] * (1.f / 32.f);
}

// ---------------- direct conv: 8x32 spatial tile, 32 in-ch in LDS ----------------
#define TH 8
#define TW 32

__global__ __launch_bounds__(256, 3) void conv_kernel(const float* __restrict__ x,
                                                      const float* __restrict__ kw,
                                                      float* __restrict__ out)
{
    __shared__ float sx[32][TH + 2][TW + 2];  // 32*10*34*4 = 43520 B

    const int x0t = blockIdx.x * TW;
    const int y0t = blockIdx.y * TH;
    const int n = blockIdx.z;
    const int tid = threadIdx.x;

    const float* xn = x + (size_t)n * 32 * 512 * 512;

    // cooperative halo load: 32*10*34 = 10880 elements
    for (int idx = tid; idx < 32 * 10 * 34; idx += 256) {
        int ch = idx / 340;
        int rem = idx - ch * 340;
        int row = rem / 34;
        int col = rem - row * 34;
        int gy = y0t + row - 1;
        int gx = x0t + col - 1;
        float v = 0.f;
        if ((unsigned)gy < 512u && (unsigned)gx < 512u)
            v = xn[((size_t)ch * 512 + gy) * 512 + gx];
        sx[ch][row][col] = v;
    }
    __syncthreads();

    const int tx = tid & 31;
    const int ty = tid >> 5;

    float acc[32];
#pragma unroll
    for (int o = 0; o < 32; ++o) acc[o] = 0.f;

#pragma unroll 1
    for (int i = 0; i < 32; ++i) {
#pragma unroll
        for (int dy = 0; dy < 3; ++dy) {
#pragma unroll
            for (int dx = 0; dx < 3; ++dx) {
                float xv = sx[i][ty + dy][tx + dx];
                const float* wp = kw + (((i * 3 + dy) * 3 + dx) << 5);  // uniform -> s_load
#pragma unroll
                for (int o = 0; o < 32; ++o) acc[o] = fmaf(xv, wp[o], acc[o]);
            }
        }
    }

    float* op = out + (((size_t)n * 32) * 512 + (y0t + ty)) * 512 + x0t + tx;
#pragma unroll
    for (int o = 0; o < 32; ++o) op[(size_t)o * 512 * 512] = acc[o];
}

extern "C" void kernel_launch(void* const* d_in, const int* in_sizes, int n_in,
                              void* d_out, int out_size, void* d_ws, size_t ws_size,
                              hipStream_t stream) {
    const float* x = (const float*)d_in[0];
    const float* fw = (const float*)d_in[1];
    float* out = (float*)d_out;
    float* kw = (float*)d_ws;  // 32*32*9 floats = 36 KB

    prep_kernel<<<dim3(4), 256, 0, stream>>>(fw, kw);
    conv_kernel<<<dim3(512 / TW, 512 / TH, 8), 256, 0, stream>>>(x, kw, out);
}

// Round 2
// 536.529 us; speedup vs baseline: 1.5933x; 1.5933x over previous
//
#include <hip/hip_runtime.h>

// RSFConv2d via MFMA implicit GEMM:
//  (1) prep: irfft2 + 32x rot/scale grid-sample mean -> 32x32x3x3 kernel,
//      written as bf16 hi/lo split, pre-packed in MFMA A-fragment layout.
//  (2) conv: per-tap 32x32 GEMM with mfma_f32_16x16x32_bf16, exact fp32
//      product via [h,l] interleaved K-packing + swapped-A second MFMA.

typedef __attribute__((ext_vector_type(8))) short bf16x8;
typedef __attribute__((ext_vector_type(4))) float f32x4;

__device__ __forceinline__ unsigned short f2bf(float f) {
    unsigned u = __float_as_uint(f);
    u = u + 0x7fffu + ((u >> 16) & 1u);  // round-to-nearest-even
    return (unsigned short)(u >> 16);
}
__device__ __forceinline__ float bf2f(unsigned short b) {
    return __uint_as_float(((unsigned)b) << 16);
}

// ---------------- kernel synthesis: one thread per (o,i) pair ----------------
__global__ __launch_bounds__(256) void prep_kernel(const float* __restrict__ fw,
                                                   unsigned short* __restrict__ wbuf)
{
    int gid = blockIdx.x * blockDim.x + threadIdx.x;
    if (gid >= 32 * 32) return;
    int o = gid >> 5;
    int i = gid & 31;

    // freq_weight[o][i][ky(3)][kx(2)][reim(2)]
    const float* f = fw + (size_t)gid * 12;
    float re[3][2], im[3][2];
#pragma unroll
    for (int ky = 0; ky < 3; ++ky)
#pragma unroll
        for (int kx = 0; kx < 2; ++kx) {
            re[ky][kx] = f[(ky * 2 + kx) * 2 + 0];
            im[ky][kx] = f[(ky * 2 + kx) * 2 + 1];
        }

    const float c3[3] = {1.f, -0.5f, -0.5f};
    const float s3[3] = {0.f, 0.86602540378443864676f, -0.86602540378443864676f};

    float base[3][3];
#pragma unroll
    for (int y = 0; y < 3; ++y)
#pragma unroll
        for (int x = 0; x < 3; ++x) {
            float sum = 0.f;
#pragma unroll
            for (int ky = 0; ky < 3; ++ky)
#pragma unroll
                for (int kx = 0; kx < 3; ++kx) {
                    float rf, mf;
                    if (kx < 2) {
                        rf = re[ky][kx];
                        mf = im[ky][kx];
                    } else {
                        int kys = (3 - ky) % 3;
                        rf = re[kys][1];
                        mf = -im[kys][1];
                    }
                    int m = (ky * y + kx * x) % 3;
                    sum += rf * c3[m] - mf * s3[m];
                }
            base[y][x] = sum * (1.f / 9.f);
        }

    const float scales[4] = {1.f, 1.25f, 1.5625f, 1.953125f};
    const float coords[3] = {-2.f / 3.f, 0.f, 2.f / 3.f};

    float acc[3][3] = {{0.f, 0.f, 0.f}, {0.f, 0.f, 0.f}, {0.f, 0.f, 0.f}};

    for (int t = 0; t < 32; ++t) {
        int r = t >> 2, si = t & 3;
        float th = (float)r * 0.78539816339744830961f;
        float sc = scales[si];
        float c = cosf(th) * sc;
        float s = sinf(th) * sc;
#pragma unroll
        for (int p = 0; p < 3; ++p) {
#pragma unroll
            for (int q = 0; q < 3; ++q) {
                float gxo = coords[q], gyo = coords[p];
                float gx = c * gxo - s * gyo;
                float gy = s * gxo + c * gyo;
                float ix = ((gx + 1.f) * 3.f - 1.f) * 0.5f;
                float iy = ((gy + 1.f) * 3.f - 1.f) * 0.5f;
                float fx0 = floorf(ix), fy0 = floorf(iy);
                int x0 = (int)fx0, y0 = (int)fy0;
                int x1 = x0 + 1, y1 = y0 + 1;
                float wx1 = ix - fx0, wy1 = iy - fy0;
                float wx0 = 1.f - wx1, wy0 = 1.f - wy1;

                float v = 0.f;
                {
                    int yc = min(max(y0, 0), 2), xc = min(max(x0, 0), 2);
                    bool ok = (x0 >= 0) & (x0 < 3) & (y0 >= 0) & (y0 < 3);
                    v += (ok ? base[yc][xc] : 0.f) * (wy0 * wx0);
                }
                {
                    int yc = min(max(y0, 0), 2), xc = min(max(x1, 0), 2);
                    bool ok = (x1 >= 0) & (x1 < 3) & (y0 >= 0) & (y0 < 3);
                    v += (ok ? base[yc][xc] : 0.f) * (wy0 * wx1);
                }
                {
                    int yc = min(max(y1, 0), 2), xc = min(max(x0, 0), 2);
                    bool ok = (x0 >= 0) & (x0 < 3) & (y1 >= 0) & (y1 < 3);
                    v += (ok ? base[yc][xc] : 0.f) * (wy1 * wx0);
                }
                {
                    int yc = min(max(y1, 0), 2), xc = min(max(x1, 0), 2);
                    bool ok = (x1 >= 0) & (x1 < 3) & (y1 >= 0) & (y1 < 3);
                    v += (ok ? base[yc][xc] : 0.f) * (wy1 * wx1);
                }
                acc[p][q] += v;
            }
        }
    }

    // Write MFMA A-fragments: wbuf[tap][chunk][var][ohalf][row16][k32] bf16.
    // chunk = i>>4, j = i&15. var0: k=2j -> wh, k=2j+1 -> wl. var1 swapped.
    const int chunk = i >> 4, j = i & 15, ohalf = o >> 4, row = o & 15;
#pragma unroll
    for (int p = 0; p < 3; ++p)
#pragma unroll
        for (int q = 0; q < 3; ++q) {
            int t = p * 3 + q;
            float w = acc[p][q] * (1.f / 32.f);
            unsigned short wh = f2bf(w);
            unsigned short wl = f2bf(w - bf2f(wh));
            size_t b = ((size_t)(((t * 2 + chunk) * 2 + 0) * 2 + ohalf) * 16 + row) * 32 + 2 * j;
            wbuf[b] = wh;
            wbuf[b + 1] = wl;
            wbuf[b + 1024] = wl;      // var stride = 2*16*32 = 1024
            wbuf[b + 1024 + 1] = wh;
        }
}

// ---------------- conv: 16x32 output tile, per-tap MFMA GEMM ----------------
#define TLH 16
#define TLW 32
// LDS: 18*34 = 612 halo pixels, 128 B each (32 ch x [hi,lo] bf16 pairs)

__global__ __launch_bounds__(256, 2) void conv_mfma(const float* __restrict__ x,
                                                    const unsigned short* __restrict__ wbuf,
                                                    float* __restrict__ out)
{
    __shared__ unsigned int slds[612 * 32];  // 78336 B

    const int x0t = blockIdx.x * TLW;
    const int y0t = blockIdx.y * TLH;
    const int n = blockIdx.z;
    const int tid = threadIdx.x;
    const float* xn = x + ((size_t)n << 5 << 18);

    // ---- stage + split-convert: x tile (with halo) -> LDS [px][k] bf16 ----
    for (int idx = tid; idx < 612 * 32; idx += 256) {
        int i = idx / 612;
        int px = idx - i * 612;
        int row = px / 34;
        int col = px - row * 34;
        int gy = y0t + row - 1;
        int gx = x0t + col - 1;
        float v = 0.f;
        if ((unsigned)gy < 512u && (unsigned)gx < 512u)
            v = xn[((size_t)i << 18) + (gy << 9) + gx];
        unsigned short h = f2bf(v);
        unsigned short l = f2bf(v - bf2f(h));
        unsigned byte = (unsigned)((px << 7) + ((i >> 4) << 6) + ((i & 15) << 2));
        byte ^= (unsigned)((px & 7) << 4);  // bank-conflict swizzle (G4)
        slds[byte >> 2] = (unsigned)h | ((unsigned)l << 16);
    }
    __syncthreads();

    // ---- MFMA phase: 4 waves, each owns 8 N-frags (16 px each) ----
    const int lane = tid & 63;
    const int wv = tid >> 6;
    const int l15 = lane & 15;
    const int kg = lane >> 4;

    f32x4 acc[8][2];
#pragma unroll
    for (int ff = 0; ff < 8; ++ff)
#pragma unroll
        for (int oh = 0; oh < 2; ++oh)
            acc[ff][oh] = (f32x4){0.f, 0.f, 0.f, 0.f};

    // A-fragment lane offset: row = lane&15, k = (lane>>4)*8 + j
    const unsigned short* wlane = wbuf + (size_t)l15 * 32 + (size_t)kg * 8;

#pragma unroll
    for (int dy = 0; dy < 3; ++dy)
#pragma unroll
        for (int dx = 0; dx < 3; ++dx) {
            const int tap = dy * 3 + dx;
#pragma unroll
            for (int chunk = 0; chunk < 2; ++chunk) {
                const unsigned short* wp = wlane + (size_t)((tap * 2 + chunk) * 4) * 512;
                bf16x8 a00 = *(const bf16x8*)(wp);          // var0, o 0-15
                bf16x8 a01 = *(const bf16x8*)(wp + 512);    // var0, o 16-31
                bf16x8 a10 = *(const bf16x8*)(wp + 1024);   // var1, o 0-15
                bf16x8 a11 = *(const bf16x8*)(wp + 1536);   // var1, o 16-31
#pragma unroll
                for (int ff = 0; ff < 8; ++ff) {
                    int fg = (wv << 3) + ff;
                    int r = fg >> 1, ch = fg & 1;
                    int px = (r + dy) * 34 + (ch << 4) + dx + l15;
                    unsigned byte = (unsigned)((px << 7) + (chunk << 6) + (kg << 4));
                    byte ^= (unsigned)((px & 7) << 4);
                    bf16x8 b = *(const bf16x8*)((const char*)slds + byte);
                    acc[ff][0] = __builtin_amdgcn_mfma_f32_16x16x32_bf16(a00, b, acc[ff][0], 0, 0, 0);
                    acc[ff][1] = __builtin_amdgcn_mfma_f32_16x16x32_bf16(a01, b, acc[ff][1], 0, 0, 0);
                    acc[ff][0] = __builtin_amdgcn_mfma_f32_16x16x32_bf16(a10, b, acc[ff][0], 0, 0, 0);
                    acc[ff][1] = __builtin_amdgcn_mfma_f32_16x16x32_bf16(a11, b, acc[ff][1], 0, 0, 0);
                }
            }
        }

    // ---- epilogue: C/D layout col=lane&15 (pixel), row=(lane>>4)*4+reg (o) ----
#pragma unroll
    for (int ff = 0; ff < 8; ++ff) {
        int fg = (wv << 3) + ff;
        int r = fg >> 1, ch = fg & 1;
        int gy = y0t + r;
        int gx = x0t + (ch << 4) + l15;
#pragma unroll
        for (int oh = 0; oh < 2; ++oh) {
            int obase = (oh << 4) + (kg << 2);
#pragma unroll
            for (int reg = 0; reg < 4; ++reg) {
                int o = obase + reg;
                out[(((size_t)(n * 32 + o) << 9) + gy << 9) + gx] = acc[ff][oh][reg];
            }
        }
    }
}

extern "C" void kernel_launch(void* const* d_in, const int* in_sizes, int n_in,
                              void* d_out, int out_size, void* d_ws, size_t ws_size,
                              hipStream_t stream) {
    const float* x = (const float*)d_in[0];
    const float* fw = (const float*)d_in[1];
    float* out = (float*)d_out;
    unsigned short* wbuf = (unsigned short*)d_ws;  // 36864 bf16 = 73728 B

    prep_kernel<<<dim3(4), 256, 0, stream>>>(fw, wbuf);
    conv_mfma<<<dim3(512 / TLW, 512 / TLH, 8), 256, 0, stream>>>(x, wbuf, out);
}

// Round 3
// 413.645 us; speedup vs baseline: 2.0666x; 1.2971x over previous
//
#include <hip/hip_runtime.h>

// RSFConv2d via MFMA implicit GEMM, round 3:
//  - x staged once per tile as SINGLE bf16 (RNE), K=32 channels per fragment
//  - weights exact via hi+lo bf16 split carried as TWO A-matrices (wh, wl)
//  - LDS = 4 K-group planes of [612 px][16 B] -> conflict-free b128 read/write
//  - 39.2 KB LDS -> 4 blocks/CU (16 waves), launch_bounds(256,4)

typedef __attribute__((ext_vector_type(8))) short bf16x8;
typedef __attribute__((ext_vector_type(4))) float f32x4;
typedef __attribute__((ext_vector_type(4))) unsigned int u32x4;

__device__ __forceinline__ unsigned short f2bf(float f) {
    unsigned u = __float_as_uint(f);
    u = u + 0x7fffu + ((u >> 16) & 1u);  // round-to-nearest-even
    return (unsigned short)(u >> 16);
}
__device__ __forceinline__ float bf2f(unsigned short b) {
    return __uint_as_float(((unsigned)b) << 16);
}

// ---------------- kernel synthesis: one thread per (o,i) pair ----------------
__global__ __launch_bounds__(256) void prep_kernel(const float* __restrict__ fw,
                                                   unsigned short* __restrict__ wbuf)
{
    int gid = blockIdx.x * blockDim.x + threadIdx.x;
    if (gid >= 32 * 32) return;
    int o = gid >> 5;
    int i = gid & 31;

    // freq_weight[o][i][ky(3)][kx(2)][reim(2)]
    const float* f = fw + (size_t)gid * 12;
    float re[3][2], im[3][2];
#pragma unroll
    for (int ky = 0; ky < 3; ++ky)
#pragma unroll
        for (int kx = 0; kx < 2; ++kx) {
            re[ky][kx] = f[(ky * 2 + kx) * 2 + 0];
            im[ky][kx] = f[(ky * 2 + kx) * 2 + 1];
        }

    const float c3[3] = {1.f, -0.5f, -0.5f};
    const float s3[3] = {0.f, 0.86602540378443864676f, -0.86602540378443864676f};

    float base[3][3];
#pragma unroll
    for (int y = 0; y < 3; ++y)
#pragma unroll
        for (int x = 0; x < 3; ++x) {
            float sum = 0.f;
#pragma unroll
            for (int ky = 0; ky < 3; ++ky)
#pragma unroll
                for (int kx = 0; kx < 3; ++kx) {
                    float rf, mf;
                    if (kx < 2) {
                        rf = re[ky][kx];
                        mf = im[ky][kx];
                    } else {
                        int kys = (3 - ky) % 3;
                        rf = re[kys][1];
                        mf = -im[kys][1];
                    }
                    int m = (ky * y + kx * x) % 3;
                    sum += rf * c3[m] - mf * s3[m];
                }
            base[y][x] = sum * (1.f / 9.f);
        }

    const float scales[4] = {1.f, 1.25f, 1.5625f, 1.953125f};
    const float coords[3] = {-2.f / 3.f, 0.f, 2.f / 3.f};

    float acc[3][3] = {{0.f, 0.f, 0.f}, {0.f, 0.f, 0.f}, {0.f, 0.f, 0.f}};

    for (int t = 0; t < 32; ++t) {
        int r = t >> 2, si = t & 3;
        float th = (float)r * 0.78539816339744830961f;
        float sc = scales[si];
        float c = cosf(th) * sc;
        float s = sinf(th) * sc;
#pragma unroll
        for (int p = 0; p < 3; ++p) {
#pragma unroll
            for (int q = 0; q < 3; ++q) {
                float gxo = coords[q], gyo = coords[p];
                float gx = c * gxo - s * gyo;
                float gy = s * gxo + c * gyo;
                float ix = ((gx + 1.f) * 3.f - 1.f) * 0.5f;
                float iy = ((gy + 1.f) * 3.f - 1.f) * 0.5f;
                float fx0 = floorf(ix), fy0 = floorf(iy);
                int x0 = (int)fx0, y0 = (int)fy0;
                int x1 = x0 + 1, y1 = y0 + 1;
                float wx1 = ix - fx0, wy1 = iy - fy0;
                float wx0 = 1.f - wx1, wy0 = 1.f - wy1;

                float v = 0.f;
                {
                    int yc = min(max(y0, 0), 2), xc = min(max(x0, 0), 2);
                    bool ok = (x0 >= 0) & (x0 < 3) & (y0 >= 0) & (y0 < 3);
                    v += (ok ? base[yc][xc] : 0.f) * (wy0 * wx0);
                }
                {
                    int yc = min(max(y0, 0), 2), xc = min(max(x1, 0), 2);
                    bool ok = (x1 >= 0) & (x1 < 3) & (y0 >= 0) & (y0 < 3);
                    v += (ok ? base[yc][xc] : 0.f) * (wy0 * wx1);
                }
                {
                    int yc = min(max(y1, 0), 2), xc = min(max(x0, 0), 2);
                    bool ok = (x0 >= 0) & (x0 < 3) & (y1 >= 0) & (y1 < 3);
                    v += (ok ? base[yc][xc] : 0.f) * (wy1 * wx0);
                }
                {
                    int yc = min(max(y1, 0), 2), xc = min(max(x1, 0), 2);
                    bool ok = (x1 >= 0) & (x1 < 3) & (y1 >= 0) & (y1 < 3);
                    v += (ok ? base[yc][xc] : 0.f) * (wy1 * wx1);
                }
                acc[p][q] += v;
            }
        }
    }

    // wbuf[((tap*2+var)*2+ohalf)*512 + row*32 + k], k = in-channel i.
    // var0 = wh, var1 = wl (exact residual). row = o&15, ohalf = o>>4.
    const int row = o & 15, ohalf = o >> 4;
#pragma unroll
    for (int p = 0; p < 3; ++p)
#pragma unroll
        for (int q = 0; q < 3; ++q) {
            int t = p * 3 + q;
            float w = acc[p][q] * (1.f / 32.f);
            unsigned short wh = f2bf(w);
            unsigned short wl = f2bf(w - bf2f(wh));
            size_t b = (size_t)((t * 2 + 0) * 2 + ohalf) * 512 + row * 32 + i;
            wbuf[b] = wh;
            wbuf[b + 1024] = wl;  // var stride = 2*512
        }
}

// ---------------- conv: 16x32 output tile, per-tap MFMA GEMM ----------------
#define TLH 16
#define TLW 32
#define NPX 612              // (16+2)*(32+2) halo pixels
#define PLANE_B 9792         // NPX * 16 bytes per K-group plane

__global__ __launch_bounds__(256, 4) void conv_mfma(const float* __restrict__ x,
                                                    const unsigned short* __restrict__ wbuf,
                                                    float* __restrict__ out)
{
    // 4 planes (K-groups of 8 channels) x [612 px][16 B] = 39168 B
    __shared__ unsigned int slds[4 * NPX * 4];

    const int x0t = blockIdx.x * TLW;
    const int y0t = blockIdx.y * TLH;
    const int n = blockIdx.z;
    const int tid = threadIdx.x;
    const float* xn = x + ((size_t)n << 23);  // n * 32 * 512 * 512

    // ---- stage: pack 8 channels (one plane) per px into 16 B, b128 write ----
    for (int t = tid; t < 4 * NPX; t += 256) {
        int plane = t / NPX;
        int px = t - plane * NPX;
        int row = px / 34;
        int col = px - row * 34;
        int gy = y0t + row - 1;
        int gx = x0t + col - 1;
        bool ok = ((unsigned)gy < 512u) & ((unsigned)gx < 512u);
        const float* src = xn + (((size_t)plane << 3) << 18) + ((gy << 9) + gx);
        u32x4 d;
#pragma unroll
        for (int j = 0; j < 4; ++j) {
            float v0 = ok ? src[(size_t)(2 * j) << 18] : 0.f;
            float v1 = ok ? src[(size_t)(2 * j + 1) << 18] : 0.f;
            d[j] = (unsigned)f2bf(v0) | ((unsigned)f2bf(v1) << 16);
        }
        *(u32x4*)((char*)slds + plane * PLANE_B + px * 16) = d;
    }
    __syncthreads();

    // ---- MFMA: 4 waves x 8 pixel-fragments, K=32 channels per fragment ----
    const int lane = tid & 63;
    const int wv = tid >> 6;
    const int l15 = lane & 15;
    const int kg = lane >> 4;

    f32x4 acc[8][2];
#pragma unroll
    for (int ff = 0; ff < 8; ++ff)
#pragma unroll
        for (int oh = 0; oh < 2; ++oh)
            acc[ff][oh] = (f32x4){0.f, 0.f, 0.f, 0.f};

    // A lane offset: row = lane&15, k = (lane>>4)*8 + j
    const unsigned short* wlane = wbuf + l15 * 32 + kg * 8;
    const char* bplane = (const char*)slds + kg * PLANE_B;

#pragma unroll
    for (int dy = 0; dy < 3; ++dy)
#pragma unroll
        for (int dx = 0; dx < 3; ++dx) {
            const int tap = dy * 3 + dx;
            const unsigned short* wp = wlane + tap * 2048;
            bf16x8 a00 = *(const bf16x8*)(wp);          // wh, o 0-15
            bf16x8 a01 = *(const bf16x8*)(wp + 512);    // wh, o 16-31
            bf16x8 a10 = *(const bf16x8*)(wp + 1024);   // wl, o 0-15
            bf16x8 a11 = *(const bf16x8*)(wp + 1536);   // wl, o 16-31
#pragma unroll
            for (int ff = 0; ff < 8; ++ff) {
                int fg = (wv << 3) + ff;
                int r = fg >> 1, ch = fg & 1;
                int px = (r + dy) * 34 + (ch << 4) + dx + l15;
                bf16x8 b = *(const bf16x8*)(bplane + px * 16);
                acc[ff][0] = __builtin_amdgcn_mfma_f32_16x16x32_bf16(a00, b, acc[ff][0], 0, 0, 0);
                acc[ff][1] = __builtin_amdgcn_mfma_f32_16x16x32_bf16(a01, b, acc[ff][1], 0, 0, 0);
                acc[ff][0] = __builtin_amdgcn_mfma_f32_16x16x32_bf16(a10, b, acc[ff][0], 0, 0, 0);
                acc[ff][1] = __builtin_amdgcn_mfma_f32_16x16x32_bf16(a11, b, acc[ff][1], 0, 0, 0);
            }
        }

    // ---- epilogue: C/D col = lane&15 (px), row = (lane>>4)*4+reg (o mod 16) ----
#pragma unroll
    for (int ff = 0; ff < 8; ++ff) {
        int fg = (wv << 3) + ff;
        int r = fg >> 1, ch = fg & 1;
        int gy = y0t + r;
        int gx = x0t + (ch << 4) + l15;
#pragma unroll
        for (int oh = 0; oh < 2; ++oh) {
#pragma unroll
            for (int reg = 0; reg < 4; ++reg) {
                int o = (oh << 4) + (kg << 2) + reg;
                out[((size_t)(n * 32 + o) << 18) + (gy << 9) + gx] = acc[ff][oh][reg];
            }
        }
    }
}

extern "C" void kernel_launch(void* const* d_in, const int* in_sizes, int n_in,
                              void* d_out, int out_size, void* d_ws, size_t ws_size,
                              hipStream_t stream) {
    const float* x = (const float*)d_in[0];
    const float* fw = (const float*)d_in[1];
    float* out = (float*)d_out;
    unsigned short* wbuf = (unsigned short*)d_ws;  // 9*4*512 bf16 = 36864 B

    prep_kernel<<<dim3(4), 256, 0, stream>>>(fw, wbuf);
    conv_mfma<<<dim3(512 / TLW, 512 / TLH, 8), 256, 0, stream>>>(x, wbuf, out);
}

// Round 4
// 236.904 us; speedup vs baseline: 3.6084x; 1.7460x over previous
//
#include <hip/hip_runtime.h>

// RSFConv2d round 4: 32x32x16 MFMA implicit GEMM.
//  - x staged per tile as bf16 (RNE); weights exact via wh+wl bf16 split.
//  - B-frag: col = px (lane&31) -> epilogue stores FULL 128B lines (fixes the
//    R3 write amplification: WRITE was 2.9x ideal from 64B partial segments).
//  - LDS [px][64B] with slot XOR swizzle -> conflict-free b128 read/write.
//  - 512 thr (8 waves), wave = 2 out rows x 32 o; nontemporal stores.

typedef __attribute__((ext_vector_type(8))) short bf16x8;
typedef __attribute__((ext_vector_type(16))) float f32x16;
typedef __attribute__((ext_vector_type(4))) unsigned int u32x4;

__device__ __forceinline__ unsigned short f2bf(float f) {
    unsigned u = __float_as_uint(f);
    u = u + 0x7fffu + ((u >> 16) & 1u);  // round-to-nearest-even
    return (unsigned short)(u >> 16);
}
__device__ __forceinline__ float bf2f(unsigned short b) {
    return __uint_as_float(((unsigned)b) << 16);
}

// ---------------- kernel synthesis: one thread per (o,i) pair ----------------
__global__ __launch_bounds__(256) void prep_kernel(const float* __restrict__ fw,
                                                   unsigned short* __restrict__ wbuf)
{
    int gid = blockIdx.x * blockDim.x + threadIdx.x;
    if (gid >= 32 * 32) return;
    int o = gid >> 5;
    int i = gid & 31;

    // freq_weight[o][i][ky(3)][kx(2)][reim(2)]
    const float* f = fw + (size_t)gid * 12;
    float re[3][2], im[3][2];
#pragma unroll
    for (int ky = 0; ky < 3; ++ky)
#pragma unroll
        for (int kx = 0; kx < 2; ++kx) {
            re[ky][kx] = f[(ky * 2 + kx) * 2 + 0];
            im[ky][kx] = f[(ky * 2 + kx) * 2 + 1];
        }

    const float c3[3] = {1.f, -0.5f, -0.5f};
    const float s3[3] = {0.f, 0.86602540378443864676f, -0.86602540378443864676f};

    float base[3][3];
#pragma unroll
    for (int y = 0; y < 3; ++y)
#pragma unroll
        for (int x = 0; x < 3; ++x) {
            float sum = 0.f;
#pragma unroll
            for (int ky = 0; ky < 3; ++ky)
#pragma unroll
                for (int kx = 0; kx < 3; ++kx) {
                    float rf, mf;
                    if (kx < 2) {
                        rf = re[ky][kx];
                        mf = im[ky][kx];
                    } else {
                        int kys = (3 - ky) % 3;
                        rf = re[kys][1];
                        mf = -im[kys][1];
                    }
                    int m = (ky * y + kx * x) % 3;
                    sum += rf * c3[m] - mf * s3[m];
                }
            base[y][x] = sum * (1.f / 9.f);
        }

    const float scales[4] = {1.f, 1.25f, 1.5625f, 1.953125f};
    const float coords[3] = {-2.f / 3.f, 0.f, 2.f / 3.f};

    float acc[3][3] = {{0.f, 0.f, 0.f}, {0.f, 0.f, 0.f}, {0.f, 0.f, 0.f}};

    for (int t = 0; t < 32; ++t) {
        int r = t >> 2, si = t & 3;
        float th = (float)r * 0.78539816339744830961f;
        float sc = scales[si];
        float c = cosf(th) * sc;
        float s = sinf(th) * sc;
#pragma unroll
        for (int p = 0; p < 3; ++p) {
#pragma unroll
            for (int q = 0; q < 3; ++q) {
                float gxo = coords[q], gyo = coords[p];
                float gx = c * gxo - s * gyo;
                float gy = s * gxo + c * gyo;
                float ix = ((gx + 1.f) * 3.f - 1.f) * 0.5f;
                float iy = ((gy + 1.f) * 3.f - 1.f) * 0.5f;
                float fx0 = floorf(ix), fy0 = floorf(iy);
                int x0 = (int)fx0, y0 = (int)fy0;
                int x1 = x0 + 1, y1 = y0 + 1;
                float wx1 = ix - fx0, wy1 = iy - fy0;
                float wx0 = 1.f - wx1, wy0 = 1.f - wy1;

                float v = 0.f;
                {
                    int yc = min(max(y0, 0), 2), xc = min(max(x0, 0), 2);
                    bool ok = (x0 >= 0) & (x0 < 3) & (y0 >= 0) & (y0 < 3);
                    v += (ok ? base[yc][xc] : 0.f) * (wy0 * wx0);
                }
                {
                    int yc = min(max(y0, 0), 2), xc = min(max(x1, 0), 2);
                    bool ok = (x1 >= 0) & (x1 < 3) & (y0 >= 0) & (y0 < 3);
                    v += (ok ? base[yc][xc] : 0.f) * (wy0 * wx1);
                }
                {
                    int yc = min(max(y1, 0), 2), xc = min(max(x0, 0), 2);
                    bool ok = (x0 >= 0) & (x0 < 3) & (y1 >= 0) & (y1 < 3);
                    v += (ok ? base[yc][xc] : 0.f) * (wy1 * wx0);
                }
                {
                    int yc = min(max(y1, 0), 2), xc = min(max(x1, 0), 2);
                    bool ok = (x1 >= 0) & (x1 < 3) & (y1 >= 0) & (y1 < 3);
                    v += (ok ? base[yc][xc] : 0.f) * (wy1 * wx1);
                }
                acc[p][q] += v;
            }
        }
    }

    // wbuf[(tap*2+hl)*1024 + o*32 + i]: A-matrix rows = o (0..31), k = i.
#pragma unroll
    for (int p = 0; p < 3; ++p)
#pragma unroll
        for (int q = 0; q < 3; ++q) {
            int t = p * 3 + q;
            float w = acc[p][q] * (1.f / 32.f);
            unsigned short wh = f2bf(w);
            unsigned short wl = f2bf(w - bf2f(wh));
            size_t b = (size_t)(t * 2) * 1024 + o * 32 + i;
            wbuf[b] = wh;
            wbuf[b + 1024] = wl;
        }
}

// ---------------- conv: 16x32 tile, 8 waves, 32x32x16 MFMA ----------------
#define TLH 16
#define TLW 32
#define NPX 612  // 18*34 halo pixels, 64 B each (32 ch bf16)

__global__ __launch_bounds__(512, 4) void conv_mfma(const float* __restrict__ x,
                                                    const unsigned short* __restrict__ wbuf,
                                                    float* __restrict__ out)
{
    __shared__ unsigned int slds[NPX * 16];  // 39168 B

    const int x0t = blockIdx.x * TLW;
    const int y0t = blockIdx.y * TLH;
    const int n = blockIdx.z;
    const int tid = threadIdx.x;
    const float* xn = x + ((size_t)n << 23);

    // ---- stage: pack channel-octet c of each px into 16 B, swizzled slot ----
    for (int t = tid; t < 4 * NPX; t += 512) {
        int c = t / NPX;             // channel octet 0..3 (ch 8c..8c+7)
        int px = t - c * NPX;
        int row = px / 34;
        int col = px - row * 34;
        int gy = y0t + row - 1;
        int gx = x0t + col - 1;
        bool ok = ((unsigned)gy < 512u) & ((unsigned)gx < 512u);
        const float* src = xn + (((size_t)c << 3) << 18) + ((gy << 9) + gx);
        u32x4 d;
#pragma unroll
        for (int j = 0; j < 4; ++j) {
            float v0 = ok ? src[(size_t)(2 * j) << 18] : 0.f;
            float v1 = ok ? src[(size_t)(2 * j + 1) << 18] : 0.f;
            d[j] = (unsigned)f2bf(v0) | ((unsigned)f2bf(v1) << 16);
        }
        unsigned byte = (unsigned)(px * 64) + (((unsigned)c << 4) ^ (((unsigned)px & 3u) << 4));
        *(u32x4*)((char*)slds + byte) = d;
    }
    __syncthreads();

    // ---- MFMA: wave wv owns out rows {2wv, 2wv+1}, all 32 o ----
    const int lane = tid & 63;
    const int wv = tid >> 6;
    const int pxl = lane & 31;  // B col = pixel
    const int kh = lane >> 5;   // B k-half
    const int r0 = wv << 1;

    f32x16 acc[2];
#pragma unroll
    for (int f = 0; f < 2; ++f)
#pragma unroll
        for (int r = 0; r < 16; ++r) acc[f][r] = 0.f;

#pragma unroll 1
    for (int dy = 0; dy < 3; ++dy) {
        // A-frags for this dy: lane holds row o=pxl, k = kh*8 + j of K=16
        bf16x8 A[3][2][2];  // [dx][hl][kstep]
#pragma unroll
        for (int dx = 0; dx < 3; ++dx)
#pragma unroll
            for (int hl = 0; hl < 2; ++hl)
#pragma unroll
                for (int ks = 0; ks < 2; ++ks) {
                    int tap = dy * 3 + dx;
                    A[dx][hl][ks] = *(const bf16x8*)(wbuf + (size_t)(tap * 2 + hl) * 1024 +
                                                     pxl * 32 + ks * 16 + kh * 8);
                }
#pragma unroll
        for (int f = 0; f < 2; ++f) {
            int lrow = r0 + f + dy;  // LDS row (0 = global y0t-1)
#pragma unroll
            for (int dx = 0; dx < 3; ++dx) {
                int px = lrow * 34 + dx + pxl;
#pragma unroll
                for (int ks = 0; ks < 2; ++ks) {
                    unsigned slot = (((unsigned)(ks * 2 + kh)) << 4) ^ (((unsigned)px & 3u) << 4);
                    bf16x8 b = *(const bf16x8*)((const char*)slds + px * 64 + slot);
                    acc[f] = __builtin_amdgcn_mfma_f32_32x32x16_bf16(A[dx][0][ks], b, acc[f], 0, 0, 0);
                    acc[f] = __builtin_amdgcn_mfma_f32_32x32x16_bf16(A[dx][1][ks], b, acc[f], 0, 0, 0);
                }
            }
        }
    }

    // ---- epilogue: C/D col=lane&31 (px), row=(reg&3)+8*(reg>>2)+4*(lane>>5) (o)
    // one store inst = 2 o-planes x 128 B full lines, nontemporal
#pragma unroll
    for (int f = 0; f < 2; ++f) {
        int gy = y0t + r0 + f;
#pragma unroll
        for (int reg = 0; reg < 16; ++reg) {
            int o = (reg & 3) + 8 * (reg >> 2) + 4 * kh;
            size_t idx = ((size_t)(n * 32 + o) << 18) + (size_t)(gy << 9) + x0t + pxl;
            __builtin_nontemporal_store(acc[f][reg], &out[idx]);
        }
    }
}

extern "C" void kernel_launch(void* const* d_in, const int* in_sizes, int n_in,
                              void* d_out, int out_size, void* d_ws, size_t ws_size,
                              hipStream_t stream) {
    const float* x = (const float*)d_in[0];
    const float* fw = (const float*)d_in[1];
    float* out = (float*)d_out;
    unsigned short* wbuf = (unsigned short*)d_ws;  // 18*1024 bf16 = 36864 B

    prep_kernel<<<dim3(4), 256, 0, stream>>>(fw, wbuf);
    conv_mfma<<<dim3(512 / TLW, 512 / TLH, 8), 512, 0, stream>>>(x, wbuf, out);
}